// Round 6
// baseline (512.987 us; speedup 1.0000x reference)
//
#include <hip/hip_runtime.h>
#include <math.h>
#include <stdint.h>

#define DIM 16
#define N_LAYERS 3
#define LSTEPS 10

// Build M = scatter(Q into strict lower tri); M = M^T + M  (16x16, zero diag)
// All values exact (adds with 0), so f32 build is bitwise == reference's.
__global__ void build_M_kernel(const float* __restrict__ Q, float* __restrict__ M) {
    int t = threadIdx.x;
    if (t < DIM * DIM) {
        int i = t >> 4, j = t & (DIM - 1);
        float v = 0.0f;
        if (i != j) {
            int a = i > j ? i : j;
            int c = i > j ? j : i;
            v = Q[(a * (a - 1)) / 2 + c];
        }
        M[t] = v;
    }
}

// Eigen generic_fast_tanh_float with EIGEN_VECTORIZE_FMA defined ==
// XLA llvm_ir::EmitFastTanh(with_fma=true), the path taken on any FMA-capable
// x86 host (AVX2/AVX512):
//   clamp to +-7.99881172180175781 (NOT 7.90531... — that's the no-FMA path)
//   P,Q Horner chains via fused multiply-add; x*P and x*x plain mul
//   IEEE divide; |x| < 4e-4 -> x passthrough (on the ORIGINAL x)
__device__ __forceinline__ float xla_tanh(float x) {
    #pragma clang fp contract(off)
    float xc = fmaxf(fminf(x, 7.99881172180175781f), -7.99881172180175781f);
    float x2 = xc * xc;
    float p = fmaf(x2, -2.76076847742355e-16f, 2.00018790482477e-13f); // a13 -> a11
    p = fmaf(x2, p, -8.60467152213735e-11f);   // a9
    p = fmaf(x2, p,  5.12229709037114e-08f);   // a7
    p = fmaf(x2, p,  1.48572235717979e-05f);   // a5
    p = fmaf(x2, p,  6.37261928875436e-04f);   // a3
    p = fmaf(x2, p,  4.89352455891786e-03f);   // a1
    float num = xc * p;
    float q = fmaf(x2, 1.19825839466702e-06f, 1.18534705686654e-04f);  // b6 -> b4
    q = fmaf(x2, q, 2.26843463243900e-03f);    // b2
    q = fmaf(x2, q, 4.89352518554385e-03f);    // b0
    float r = num / q;
    return (fabsf(x) < 4e-4f) ? x : r;
}

__global__ __launch_bounds__(256) void ising_kernel(
    const float* __restrict__ M,      // 16x16 (in d_ws), wave-uniform reads
    const float* __restrict__ delta,  // 16
    const float* __restrict__ y0,     // batch x 16
    const float* __restrict__ vnoise, // 3 x batch x 16
    float* __restrict__ xout,         // batch x 16 (f32)
    float* __restrict__ eout,         // batch (f32)
    int batch)
{
    #pragma clang fp contract(off)   // reference (XLA CPU, fast-math off) never contracts;
                                     // fused ops appear ONLY as explicit fmaf below
    int b = blockIdx.x * blockDim.x + threadIdx.x;
    if (b >= batch) return;

    float y[DIM], x[DIM], vel[DIM], f[DIM];

    {
        const float4* yv = reinterpret_cast<const float4*>(y0 + (size_t)b * DIM);
        #pragma unroll
        for (int q = 0; q < 4; ++q) {
            float4 v = yv[q];
            y[4*q+0] = v.x; y[4*q+1] = v.y; y[4*q+2] = v.z; y[4*q+3] = v.w;
        }
    }

    // x = tanh(y0)
    #pragma unroll
    for (int i = 0; i < DIM; ++i) x[i] = xla_tanh(y[i]);

    // f = force(x) = (delta + x@M) * (1 - x*x)
    // dot: ascending-k fused chain (Eigen gebp / oneDNN sgemm accumulate with
    // vfmadd, single chain ascending k); elementwise: plain ops.
    #pragma unroll
    for (int i = 0; i < DIM; ++i) {
        float acc = 0.0f;
        #pragma unroll
        for (int k = 0; k < DIM; ++k) acc = fmaf(x[k], M[k*DIM + i], acc);
        float s  = delta[i] + acc;
        float xx = x[i] * x[i];
        float om = 1.0f - xx;
        f[i] = s * om;
    }

    #pragma unroll 1
    for (int l = 0; l < N_LAYERS; ++l) {
        {
            const float4* vv = reinterpret_cast<const float4*>(vnoise + ((size_t)l * batch + b) * DIM);
            #pragma unroll
            for (int q = 0; q < 4; ++q) {
                float4 v = vv[q];
                vel[4*q+0] = v.x; vel[4*q+1] = v.y; vel[4*q+2] = v.z; vel[4*q+3] = v.w;
            }
        }
        #pragma unroll 1
        for (int s = 0; s < LSTEPS; ++s) {
            // vel_half = vel + 0.5*f;  y = y + vel_half   (plain mul/add)
            #pragma unroll
            for (int i = 0; i < DIM; ++i) {
                float hf = 0.5f * f[i];
                float vh = vel[i] + hf;
                y[i] = y[i] + vh;
                vel[i] = vh;   // holds vel_half
            }
            // globally-last step: force/vel are dead (vel discarded; x_out needs only y)
            if (l == N_LAYERS - 1 && s == LSTEPS - 1) break;

            #pragma unroll
            for (int i = 0; i < DIM; ++i) x[i] = xla_tanh(y[i]);

            // f = force(x_new); vel = vel_half + 0.5*f
            // (f reused as next step's leading force — reference recomputes force(x)
            //  on an identical x with identical ops => bitwise identical)
            #pragma unroll
            for (int i = 0; i < DIM; ++i) {
                float acc = 0.0f;
                #pragma unroll
                for (int k = 0; k < DIM; ++k) acc = fmaf(x[k], M[k*DIM + i], acc);
                float sfc = delta[i] + acc;
                float xx  = x[i] * x[i];
                float om  = 1.0f - xx;
                float fi  = sfc * om;
                f[i] = fi;
                float hf = 0.5f * fi;
                vel[i] = vel[i] + hf;
            }
        }
    }

    // Straight-through output, bitwise as the reference computes it:
    //   z = y; t = tanh(z); hard = sign(sign(z) - 1e-6); x_out = (hard - t) + t
    float xo[DIM];
    #pragma unroll
    for (int i = 0; i < DIM; ++i) {
        float z = y[i];
        float t = xla_tanh(z);
        float s1 = (z > 0.0f) ? 1.0f : ((z < 0.0f) ? -1.0f : 0.0f);
        float s2 = s1 - 1e-6f;
        float hard = (s2 > 0.0f) ? 1.0f : -1.0f;  // never 0 after the shift
        float d = hard - t;
        xo[i] = d + t;
    }

    // energy = sum_i ((0.5*(xo@M)_i) * xo_i + delta_i * xo_i), ascending from 0
    float e = 0.0f;
    #pragma unroll
    for (int i = 0; i < DIM; ++i) {
        float h = 0.0f;
        #pragma unroll
        for (int k = 0; k < DIM; ++k) h = fmaf(xo[k], M[k*DIM + i], h);
        float t1 = 0.5f * h;
        float t2 = t1 * xo[i];
        float t3 = delta[i] * xo[i];
        float el = t2 + t3;
        e = e + el;
    }

    {
        float4* ov = reinterpret_cast<float4*>(xout + (size_t)b * DIM);
        #pragma unroll
        for (int q = 0; q < 4; ++q) {
            float4 v;
            v.x = xo[4*q+0]; v.y = xo[4*q+1]; v.z = xo[4*q+2]; v.w = xo[4*q+3];
            ov[q] = v;
        }
        eout[b] = e;
    }
}

extern "C" void kernel_launch(void* const* d_in, const int* in_sizes, int n_in,
                              void* d_out, int out_size, void* d_ws, size_t ws_size,
                              hipStream_t stream) {
    // inputs order: inputs(B,1), Q(120), delta(16), y0(B,16), vel_noise(3,B,16)
    const float* Q     = (const float*)d_in[1];
    const float* delta = (const float*)d_in[2];
    const float* y0    = (const float*)d_in[3];
    const float* vn    = (const float*)d_in[4];
    int batch = in_sizes[3] / DIM;

    float* M    = (float*)d_ws;               // 256 floats scratch
    float* xout = (float*)d_out;              // batch*16 f32
    float* eout = xout + (size_t)batch * DIM; // batch f32

    build_M_kernel<<<1, 256, 0, stream>>>(Q, M);
    int blocks = (batch + 255) / 256;
    ising_kernel<<<dim3(blocks), dim3(256), 0, stream>>>(M, delta, y0, vn, xout, eout, batch);
}